// Round 8
// baseline (245.386 us; speedup 1.0000x reference)
//
#include <hip/hip_runtime.h>
#include <hip/hip_bf16.h>

// ---------- common types ----------
typedef __attribute__((ext_vector_type(8))) short bf16x8;
typedef __attribute__((ext_vector_type(4))) float f32x4;

__device__ __forceinline__ ushort f2bf(float f) {
  unsigned int u = __float_as_uint(f);
  u += 0x7fffu + ((u >> 16) & 1u);   // RNE
  return (ushort)(u >> 16);
}

__device__ __forceinline__ void gl_lds16(const void* g, void* l) {
  __builtin_amdgcn_global_load_lds(
      (const __attribute__((address_space(1))) void*)g,
      (__attribute__((address_space(3))) void*)l, 16, 0, 0);
}

#define SB() __builtin_amdgcn_sched_barrier(0)

// ---------- weight convert+transpose: W[K][N] f32 -> Wt[N][K] bf16 ----------
__global__ __launch_bounds__(256) void transpose_w(
    const float* __restrict__ W, ushort* __restrict__ Wt, int K, int N) {
  __shared__ float tile[32][33];
  const int tx = threadIdx.x, ty = threadIdx.y;  // (32, 8)
  const int bx = blockIdx.x, by = blockIdx.y;
#pragma unroll
  for (int j = 0; j < 4; j++)
    tile[ty + j * 8][tx] = W[(size_t)(by * 32 + ty + j * 8) * N + bx * 32 + tx];
  __syncthreads();
#pragma unroll
  for (int j = 0; j < 4; j++)
    Wt[(size_t)(bx * 32 + ty + j * 8) * K + by * 32 + tx] =
        f2bf(tile[tx][ty + j * 8]);
}

// ---------- V transpose: qkv V-part -> vt[bh][d][n] bf16 ----------
__global__ __launch_bounds__(256) void transpose_v(
    const ushort* __restrict__ qkv, ushort* __restrict__ vt) {
  __shared__ ushort tile[32][33];
  const int tx = threadIdx.x, ty = threadIdx.y;  // (32, 8)
  const int n0 = blockIdx.x * 32;
  const int d0 = blockIdx.y * 32;
  const int bh = blockIdx.z;
  const int bidx = bh >> 4, h = bh & 15;
#pragma unroll
  for (int j = 0; j < 4; j++)
    tile[ty + j * 8][tx] =
        qkv[(size_t)(bidx * 1024 + n0 + ty + j * 8) * 3072 + 2048 + h * 64 +
            d0 + tx];
  __syncthreads();
#pragma unroll
  for (int j = 0; j < 4; j++)
    vt[(size_t)(bh * 64 + d0 + ty + j * 8) * 1024 + n0 + tx] =
        tile[tx][ty + j * 8];
}

// ---------- layernorm: f32 row(1024) -> bf16 ----------
__global__ __launch_bounds__(256) void ln_bf16(
    const float* __restrict__ x, const float* __restrict__ g,
    const float* __restrict__ b, ushort* __restrict__ out) {
  const int row = blockIdx.x;
  const int t = threadIdx.x;
  float4 v = ((const float4*)(x + (size_t)row * 1024))[t];
  float s = v.x + v.y + v.z + v.w;
  float ss = v.x * v.x + v.y * v.y + v.z * v.z + v.w * v.w;
#pragma unroll
  for (int msk = 1; msk < 64; msk <<= 1) {
    s += __shfl_xor(s, msk);
    ss += __shfl_xor(ss, msk);
  }
  __shared__ float red[8];
  const int wv = t >> 6, ln = t & 63;
  if (ln == 0) { red[wv * 2] = s; red[wv * 2 + 1] = ss; }
  __syncthreads();
  s = red[0] + red[2] + red[4] + red[6];
  ss = red[1] + red[3] + red[5] + red[7];
  const float mu = s * (1.0f / 1024.0f);
  const float var = ss * (1.0f / 1024.0f) - mu * mu;
  const float rstd = rsqrtf(var + 1e-5f);
  float4 gv = ((const float4*)g)[t];
  float4 bv = ((const float4*)b)[t];
  ushort4 o;
  o.x = f2bf((v.x - mu) * rstd * gv.x + bv.x);
  o.y = f2bf((v.y - mu) * rstd * gv.y + bv.y);
  o.z = f2bf((v.z - mu) * rstd * gv.z + bv.z);
  o.w = f2bf((v.w - mu) * rstd * gv.w + bv.w);
  ((ushort4*)(out + (size_t)row * 1024))[t] = o;
}

// ---------- 2-phase double-buffered GEMM, BK=32 ----------
// C[M][N] = A[M][K](bf16) * Bt[N][K]^T(bf16) + bias, epilogue by EPI.
// EPI 0: bias -> bf16. EPI 1: bias+GELU -> bf16. EPI 2: bias+resid(f32) -> f32.
// Sync: ONE vmcnt(0) + barrier per K-tile (deterministic regardless of extra
// codegen vmem ops). BK=32 halves LDS vs r7 (128^2: 32 KB) -> 4 blocks/CU
// co-resident (the drain-hiding mechanism; r7 had 2/CU and MfmaUtil 15%).
// T2 swizzle for 4-unit rows: phys_unit = log_unit ^ ((row>>1)&3), applied on
// gl_lds SOURCE (dest linear) and ds_read; quarter-wave bank-group spread =
// 2 lanes/group (free, m136).
// T1 XCD-rectangle swizzle: cw*xw == gridDim.x, ch*(8/xw) == gridDim.y.
template <int BM, int BN, int NW, int OCC, int EPI>
__global__ __launch_bounds__(NW * 64, OCC) void gemm2ph(
    const ushort* __restrict__ A, const ushort* __restrict__ Bt,
    const float* __restrict__ bias, const float* __restrict__ resid,
    void* __restrict__ outp, int M, int N, int K, int cw, int ch, int xw) {
  constexpr int WN = NW / 2;         // wave cols
  constexpr int BWN = BN / WN;       // B rows per wave col
  constexpr int MF = BM / 2 / 16;    // A frags per wave
  constexpr int NF = BWN / 16;       // B frags per wave
  constexpr int CA = BM / 64, CB = BN / 64;  // 64-row staging chunks
  __shared__ ushort smem[2 * (BM + BN) * 32];
  const int t = threadIdx.x;
  const int lane = t & 63, wid = t >> 6;
  const int lr = lane & 15, lc = lane >> 4;
  const int wr = wid / WN, wc = wid % WN;

  // XCD-rectangle swizzle
  const int flat = blockIdx.y * gridDim.x + blockIdx.x;
  const int xcd = flat & 7, li = flat >> 3;
  const int bx = (xcd % xw) * cw + (li % cw);
  const int by = (xcd / xw) * ch + (li / cw);
  const int m0 = by * BM, n0 = bx * BN;
  const int nkt = K >> 5;

  // staging: chunk = 64 rows x 4 x 16B units = 256 threads x 16B.
  // thread t -> row t>>2, phys unit t&3, log unit (t&3)^((t>>3)&3).
  const int uoff = ((t & 3) ^ ((t >> 3) & 3)) * 8;
  // read: log unit lc -> phys lc ^ ((row>>1)&3); row>>1 dependence reduces
  // to (lr>>1)&3 (all other row terms are multiples of 4 after >>1).
  const int au = (lc ^ ((lr >> 1) & 3)) * 8;

  f32x4 acc[MF][NF];
#pragma unroll
  for (int m = 0; m < MF; m++)
#pragma unroll
    for (int n = 0; n < NF; n++) acc[m][n] = (f32x4){0.f, 0.f, 0.f, 0.f};

  auto stage = [&](int bb, int kt) {
#pragma unroll
    for (int c = 0; c < CA; c++)
      gl_lds16(A + (size_t)(m0 + c * 64 + (t >> 2)) * K + (size_t)(kt * 32) +
                   uoff,
               &smem[bb * BM * 32 + c * 2048 + wid * 512]);
#pragma unroll
    for (int c = 0; c < CB; c++)
      gl_lds16(Bt + (size_t)(n0 + c * 64 + (t >> 2)) * K + (size_t)(kt * 32) +
                   uoff,
               &smem[2 * BM * 32 + bb * BN * 32 + c * 2048 + wid * 512]);
  };
  auto rdA = [&](int bb, int mf) {
    return *(const bf16x8*)&smem[bb * BM * 32 +
                                 (wr * (BM / 2) + mf * 16 + lr) * 32 + au];
  };
  auto rdB = [&](int bb, int nf) {
    return *(const bf16x8*)&smem[2 * BM * 32 + bb * BN * 32 +
                                 (wc * BWN + nf * 16 + lr) * 32 + au];
  };

  // prologue
  stage(0, 0);
  asm volatile("s_waitcnt vmcnt(0)" ::: "memory");
  SB(); __builtin_amdgcn_s_barrier(); SB();

  int b = 0;
  for (int kt = 0; kt < nkt; kt++, b ^= 1) {
    if (kt + 1 < nkt) stage(b ^ 1, kt + 1);

    bf16x8 Br[NF];
#pragma unroll
    for (int nf = 0; nf < NF; nf++) Br[nf] = rdB(b, nf);
    bf16x8 Ar[MF];
#pragma unroll
    for (int mf = 0; mf < MF; mf++) Ar[mf] = rdA(b, mf);
    __builtin_amdgcn_s_setprio(1);
#pragma unroll
    for (int mf = 0; mf < MF; mf++)
#pragma unroll
      for (int nf = 0; nf < NF; nf++)
        acc[mf][nf] = __builtin_amdgcn_mfma_f32_16x16x32_bf16(
            Ar[mf], Br[nf], acc[mf][nf], 0, 0, 0);
    __builtin_amdgcn_s_setprio(0);

    asm volatile("s_waitcnt vmcnt(0)" ::: "memory");
    SB(); __builtin_amdgcn_s_barrier(); SB();
  }

  // epilogue
#pragma unroll
  for (int mf = 0; mf < MF; mf++) {
#pragma unroll
    for (int nf = 0; nf < NF; nf++) {
      const int gr0 = m0 + wr * (BM / 2) + mf * 16 + lc * 4;
      const int gc = n0 + wc * BWN + nf * 16 + lr;
      const float bs = bias[gc];
#pragma unroll
      for (int r = 0; r < 4; r++) {
        const float v = acc[mf][nf][r] + bs;
        const int gr = gr0 + r;
        if (EPI == 0) {
          ((ushort*)outp)[(size_t)gr * N + gc] = f2bf(v);
        } else if (EPI == 1) {
          const float gg = 0.5f * v * (1.0f + erff(v * 0.70710678118654752f));
          ((ushort*)outp)[(size_t)gr * N + gc] = f2bf(gg);
        } else {
          ((float*)outp)[(size_t)gr * N + gc] =
              v + resid[(size_t)gr * N + gc];
        }
      }
    }
  }
}

// ---------- flash attention (swapped operands) ----------
__global__ __launch_bounds__(256) void attn_kernel(
    const ushort* __restrict__ qkv, const ushort* __restrict__ vt,
    ushort* __restrict__ o_out) {
  __shared__ ushort sK[4096];
  __shared__ ushort sV[4096];
  __shared__ ushort sP[4 * 32 * 72];
  const int t = threadIdx.x;
  const int lane = t & 63, wid = t >> 6;
  const int lr = lane & 15, lc = lane >> 4;
  const int qb = blockIdx.x;
  const int bh = blockIdx.y;
  const int bidx = bh >> 4, h = bh & 15;
  const size_t base = (size_t)bidx * 1024 * 3072;
  const int q0w = qb * 128 + wid * 32;

  bf16x8 qf[2][2];
#pragma unroll
  for (int nf = 0; nf < 2; nf++)
#pragma unroll
    for (int kd = 0; kd < 2; kd++)
      qf[nf][kd] = *(const bf16x8*)&qkv[base +
          (size_t)(q0w + nf * 16 + lr) * 3072 + h * 64 + kd * 32 + lc * 8];

  f32x4 oacc[4][2];
#pragma unroll
  for (int mf = 0; mf < 4; mf++)
#pragma unroll
    for (int nf = 0; nf < 2; nf++) oacc[mf][nf] = (f32x4){0.f, 0.f, 0.f, 0.f};
  float m_r[2] = {-1e30f, -1e30f};
  float l_r[2] = {0.f, 0.f};

  const int srow = lane >> 2;
  const int scol = (lane & 3) * 8;
  ushort* pw = sP + wid * 2304;

  for (int kv0 = 0; kv0 < 1024; kv0 += 64) {
    __syncthreads();
#pragma unroll
    for (int s = 0; s < 2; s++) {
      gl_lds16(qkv + base + (size_t)(kv0 + wid * 16 + srow) * 3072 + 1024 +
                   h * 64 + s * 32 + scol,
               sK + s * 2048 + wid * 512);
      gl_lds16(vt + (size_t)(bh * 64 + wid * 16 + srow) * 1024 + kv0 + s * 32 +
                   scol,
               sV + s * 2048 + wid * 512);
    }
    __syncthreads();

    f32x4 st[4][2];
#pragma unroll
    for (int mf = 0; mf < 4; mf++) {
      bf16x8 ka0 = *(const bf16x8*)&sK[(mf * 16 + lr) * 32 + lc * 8];
      bf16x8 ka1 = *(const bf16x8*)&sK[2048 + (mf * 16 + lr) * 32 + lc * 8];
#pragma unroll
      for (int nf = 0; nf < 2; nf++) {
        f32x4 z = (f32x4){0.f, 0.f, 0.f, 0.f};
        z = __builtin_amdgcn_mfma_f32_16x16x32_bf16(ka0, qf[nf][0], z, 0, 0, 0);
        z = __builtin_amdgcn_mfma_f32_16x16x32_bf16(ka1, qf[nf][1], z, 0, 0, 0);
        st[mf][nf] = z;
      }
    }

#pragma unroll
    for (int nf = 0; nf < 2; nf++) {
      float mx = st[0][nf][0];
#pragma unroll
      for (int mf = 0; mf < 4; mf++)
        mx = fmaxf(mx, fmaxf(fmaxf(st[mf][nf][0], st[mf][nf][1]),
                             fmaxf(st[mf][nf][2], st[mf][nf][3])));
      mx = fmaxf(mx, __shfl_xor(mx, 16));
      mx = fmaxf(mx, __shfl_xor(mx, 32));
      mx *= 0.125f;
      const float mn = fmaxf(m_r[nf], mx);
      const float alpha = __expf(m_r[nf] - mn);
      m_r[nf] = mn;
      float rs = 0.f;
#pragma unroll
      for (int mf = 0; mf < 4; mf++) {
        const float p0 = __expf(fmaf(st[mf][nf][0], 0.125f, -mn));
        const float p1 = __expf(fmaf(st[mf][nf][1], 0.125f, -mn));
        const float p2 = __expf(fmaf(st[mf][nf][2], 0.125f, -mn));
        const float p3 = __expf(fmaf(st[mf][nf][3], 0.125f, -mn));
        rs += (p0 + p1) + (p2 + p3);
        uint2 u;
        u.x = (uint)f2bf(p0) | ((uint)f2bf(p1) << 16);
        u.y = (uint)f2bf(p2) | ((uint)f2bf(p3) << 16);
        *(uint2*)&pw[(nf * 16 + lr) * 72 + mf * 16 + lc * 4] = u;
      }
      rs += __shfl_xor(rs, 16);
      rs += __shfl_xor(rs, 32);
      l_r[nf] = l_r[nf] * alpha + rs;
#pragma unroll
      for (int mf = 0; mf < 4; mf++) {
        oacc[mf][nf][0] *= alpha;
        oacc[mf][nf][1] *= alpha;
        oacc[mf][nf][2] *= alpha;
        oacc[mf][nf][3] *= alpha;
      }
    }

#pragma unroll
    for (int ks = 0; ks < 2; ks++) {
      bf16x8 pb0 = *(const bf16x8*)&pw[lr * 72 + ks * 32 + lc * 8];
      bf16x8 pb1 = *(const bf16x8*)&pw[(16 + lr) * 72 + ks * 32 + lc * 8];
#pragma unroll
      for (int mf = 0; mf < 4; mf++) {
        bf16x8 va = *(const bf16x8*)&sV[ks * 2048 + (mf * 16 + lr) * 32 + lc * 8];
        oacc[mf][0] =
            __builtin_amdgcn_mfma_f32_16x16x32_bf16(va, pb0, oacc[mf][0], 0, 0, 0);
        oacc[mf][1] =
            __builtin_amdgcn_mfma_f32_16x16x32_bf16(va, pb1, oacc[mf][1], 0, 0, 0);
      }
    }
  }

  const float inv[2] = {1.f / l_r[0], 1.f / l_r[1]};
#pragma unroll
  for (int mf = 0; mf < 4; mf++)
#pragma unroll
    for (int nf = 0; nf < 2; nf++) {
      ushort4 o4;
      o4.x = f2bf(oacc[mf][nf][0] * inv[nf]);
      o4.y = f2bf(oacc[mf][nf][1] * inv[nf]);
      o4.z = f2bf(oacc[mf][nf][2] * inv[nf]);
      o4.w = f2bf(oacc[mf][nf][3] * inv[nf]);
      *(ushort4*)&o_out[(size_t)(bidx * 1024 + q0w + nf * 16 + lr) * 1024 +
                        h * 64 + mf * 16 + lc * 4] = o4;
    }
}

// ---------- launch ----------
extern "C" void kernel_launch(void* const* d_in, const int* in_sizes, int n_in,
                              void* d_out, int out_size, void* d_ws,
                              size_t ws_size, hipStream_t stream) {
  const float* x      = (const float*)d_in[0];
  const float* ln1_g  = (const float*)d_in[1];
  const float* ln1_b  = (const float*)d_in[2];
  const float* w_qkv  = (const float*)d_in[3];
  const float* b_qkv  = (const float*)d_in[4];
  const float* w_proj = (const float*)d_in[5];
  const float* b_proj = (const float*)d_in[6];
  const float* ln2_g  = (const float*)d_in[7];
  const float* ln2_b  = (const float*)d_in[8];
  const float* w_fc1  = (const float*)d_in[9];
  const float* b_fc1  = (const float*)d_in[10];
  const float* w_fc2  = (const float*)d_in[11];
  const float* b_fc2  = (const float*)d_in[12];
  float* out = (float*)d_out;

  ushort* ws      = (ushort*)d_ws;
  ushort* wt_qkv  = ws;                         // 3072*1024
  ushort* wt_proj = wt_qkv + 3072 * 1024;       // 1024*1024
  ushort* wt_fc1  = wt_proj + 1024 * 1024;      // 4096*1024
  ushort* wt_fc2  = wt_fc1 + 4096 * 1024;       // 1024*4096
  ushort* hbuf    = wt_fc2 + 1024 * 4096;       // 4096*1024
  ushort* qkv     = hbuf + 4096 * 1024;         // 4096*3072
  ushort* obuf    = qkv + 4096 * 3072;          // 4096*1024
  ushort* h3      = qkv;                        // aliases qkv+obuf
  ushort* vtb     = hbuf;                       // vt[64][64][1024]

  transpose_w<<<dim3(96, 32), dim3(32, 8), 0, stream>>>(w_qkv, wt_qkv, 1024, 3072);
  transpose_w<<<dim3(32, 32), dim3(32, 8), 0, stream>>>(w_proj, wt_proj, 1024, 1024);
  transpose_w<<<dim3(128, 32), dim3(32, 8), 0, stream>>>(w_fc1, wt_fc1, 1024, 4096);
  transpose_w<<<dim3(32, 128), dim3(32, 8), 0, stream>>>(w_fc2, wt_fc2, 4096, 1024);

  ln_bf16<<<4096, 256, 0, stream>>>(x, ln1_g, ln1_b, hbuf);
  // QKV: 128^2, grid 24x32=768 (3/CU). XCD rect 12x8, 2 across.
  gemm2ph<128, 128, 4, 4, 0><<<dim3(24, 32), 256, 0, stream>>>(
      hbuf, wt_qkv, b_qkv, nullptr, qkv, 4096, 3072, 1024, 12, 8, 2);
  transpose_v<<<dim3(32, 2, 64), dim3(32, 8), 0, stream>>>(qkv, vtb);
  attn_kernel<<<dim3(8, 64), 256, 0, stream>>>(qkv, vtb, obuf);
  // proj + residual: 128x64, grid 16x32=512 (2/CU). XCD rect 8x8, 2 across.
  gemm2ph<128, 64, 4, 4, 2><<<dim3(16, 32), 256, 0, stream>>>(
      obuf, wt_proj, b_proj, x, out, 4096, 1024, 1024, 8, 8, 2);
  ln_bf16<<<4096, 256, 0, stream>>>(out, ln2_g, ln2_b, hbuf);
  // fc1 + GELU: 128^2, grid 32x32=1024 (4/CU). XCD rect 16x8, 2 across.
  gemm2ph<128, 128, 4, 4, 1><<<dim3(32, 32), 256, 0, stream>>>(
      hbuf, wt_fc1, b_fc1, nullptr, h3, 4096, 4096, 1024, 16, 8, 2);
  // fc2 + residual: 128x64, grid 16x32=512 (2/CU). XCD rect 8x8, 2 across.
  gemm2ph<128, 64, 4, 4, 2><<<dim3(16, 32), 256, 0, stream>>>(
      h3, wt_fc2, b_fc2, out, out, 4096, 1024, 4096, 8, 8, 2);
}

// Round 9
// 241.638 us; speedup vs baseline: 1.0155x; 1.0155x over previous
//
#include <hip/hip_runtime.h>
#include <hip/hip_bf16.h>

// ---------- common types ----------
typedef __attribute__((ext_vector_type(8))) short bf16x8;
typedef __attribute__((ext_vector_type(4))) float f32x4;

__device__ __forceinline__ ushort f2bf(float f) {
  unsigned int u = __float_as_uint(f);
  u += 0x7fffu + ((u >> 16) & 1u);   // RNE
  return (ushort)(u >> 16);
}

__device__ __forceinline__ void gl_lds16(const void* g, void* l) {
  __builtin_amdgcn_global_load_lds(
      (const __attribute__((address_space(1))) void*)g,
      (__attribute__((address_space(3))) void*)l, 16, 0, 0);
}

#define SB() __builtin_amdgcn_sched_barrier(0)

// ---------- weight convert+transpose: W[K][N] f32 -> Wt[N][K] bf16 ----------
__global__ __launch_bounds__(256) void transpose_w(
    const float* __restrict__ W, ushort* __restrict__ Wt, int K, int N) {
  __shared__ float tile[32][33];
  const int tx = threadIdx.x, ty = threadIdx.y;  // (32, 8)
  const int bx = blockIdx.x, by = blockIdx.y;
#pragma unroll
  for (int j = 0; j < 4; j++)
    tile[ty + j * 8][tx] = W[(size_t)(by * 32 + ty + j * 8) * N + bx * 32 + tx];
  __syncthreads();
#pragma unroll
  for (int j = 0; j < 4; j++)
    Wt[(size_t)(bx * 32 + ty + j * 8) * K + by * 32 + tx] =
        f2bf(tile[tx][ty + j * 8]);
}

// ---------- V transpose: qkv V-part -> vt[bh][d][n] bf16 ----------
__global__ __launch_bounds__(256) void transpose_v(
    const ushort* __restrict__ qkv, ushort* __restrict__ vt) {
  __shared__ ushort tile[32][33];
  const int tx = threadIdx.x, ty = threadIdx.y;  // (32, 8)
  const int n0 = blockIdx.x * 32;
  const int d0 = blockIdx.y * 32;
  const int bh = blockIdx.z;
  const int bidx = bh >> 4, h = bh & 15;
#pragma unroll
  for (int j = 0; j < 4; j++)
    tile[ty + j * 8][tx] =
        qkv[(size_t)(bidx * 1024 + n0 + ty + j * 8) * 3072 + 2048 + h * 64 +
            d0 + tx];
  __syncthreads();
#pragma unroll
  for (int j = 0; j < 4; j++)
    vt[(size_t)(bh * 64 + d0 + ty + j * 8) * 1024 + n0 + tx] =
        tile[tx][ty + j * 8];
}

// ---------- layernorm: f32 row(1024) -> bf16 ----------
__global__ __launch_bounds__(256) void ln_bf16(
    const float* __restrict__ x, const float* __restrict__ g,
    const float* __restrict__ b, ushort* __restrict__ out) {
  const int row = blockIdx.x;
  const int t = threadIdx.x;
  float4 v = ((const float4*)(x + (size_t)row * 1024))[t];
  float s = v.x + v.y + v.z + v.w;
  float ss = v.x * v.x + v.y * v.y + v.z * v.z + v.w * v.w;
#pragma unroll
  for (int msk = 1; msk < 64; msk <<= 1) {
    s += __shfl_xor(s, msk);
    ss += __shfl_xor(ss, msk);
  }
  __shared__ float red[8];
  const int wv = t >> 6, ln = t & 63;
  if (ln == 0) { red[wv * 2] = s; red[wv * 2 + 1] = ss; }
  __syncthreads();
  s = red[0] + red[2] + red[4] + red[6];
  ss = red[1] + red[3] + red[5] + red[7];
  const float mu = s * (1.0f / 1024.0f);
  const float var = ss * (1.0f / 1024.0f) - mu * mu;
  const float rstd = rsqrtf(var + 1e-5f);
  float4 gv = ((const float4*)g)[t];
  float4 bv = ((const float4*)b)[t];
  ushort4 o;
  o.x = f2bf((v.x - mu) * rstd * gv.x + bv.x);
  o.y = f2bf((v.y - mu) * rstd * gv.y + bv.y);
  o.z = f2bf((v.z - mu) * rstd * gv.z + bv.z);
  o.w = f2bf((v.w - mu) * rstd * gv.w + bv.w);
  ((ushort4*)(out + (size_t)row * 1024))[t] = o;
}

// ---------- depth-2 counted pipeline GEMM, BK=32, 3 LDS buffers ----------
// C[M][N] = A[M][K](bf16) * Bt[N][K]^T(bf16) + bias, epilogue by EPI.
// EPI 0: bias -> bf16. EPI 1: bias+GELU -> bf16. EPI 2: bias+resid(f32) -> f32.
// Pipeline: buffers rb (reading, k), rb+1 (in flight, k+1), rb+2 (issuing,
// k+2). Per-wave vmcnt ledger (loop contains NO other vmem; VGPR << cap so
// no scratch): stage = SC=CA+CB instrs/wave; after stage(k+2) outstanding
// = 2*SC -> s_waitcnt vmcnt(SC) retires k+1 (FIFO). Tail: vmcnt(0).
// WAR on buf (k+2)%3 is safe: its last reader was iter k-1, whose ds_reads
// retired before the end-of-iter barrier.
// T2 swizzle (verified 0 conflicts): phys unit = log ^ ((row>>1)&3) on both
// gl_lds source and ds_read. T1 XCD-rectangle swizzle as before.
template <int BM, int BN, int NW, int OCC, int EPI>
__global__ __launch_bounds__(NW * 64, OCC) void gemm3b(
    const ushort* __restrict__ A, const ushort* __restrict__ Bt,
    const float* __restrict__ bias, const float* __restrict__ resid,
    void* __restrict__ outp, int M, int N, int K, int cw, int ch, int xw) {
  constexpr int WN = NW / 2;         // wave cols
  constexpr int BWN = BN / WN;       // B rows per wave col
  constexpr int MF = BM / 2 / 16;    // A frags per wave
  constexpr int NF = BWN / 16;       // B frags per wave
  constexpr int CA = BM / 64, CB = BN / 64;  // 64-row staging chunks
  constexpr int SC = CA + CB;        // gl_lds instrs per wave per stage
  __shared__ ushort smem[3 * (BM + BN) * 32];
  const int t = threadIdx.x;
  const int lane = t & 63, wid = t >> 6;
  const int lr = lane & 15, lc = lane >> 4;
  const int wr = wid / WN, wc = wid % WN;

  // XCD-rectangle swizzle
  const int flat = blockIdx.y * gridDim.x + blockIdx.x;
  const int xcd = flat & 7, li = flat >> 3;
  const int bx = (xcd % xw) * cw + (li % cw);
  const int by = (xcd / xw) * ch + (li / cw);
  const int m0 = by * BM, n0 = bx * BN;
  const int nkt = K >> 5;

  // staging: chunk = 64 rows x 4 x 16B units = 256 threads x 16B.
  const int uoff = ((t & 3) ^ ((t >> 3) & 3)) * 8;
  const int au = (lc ^ ((lr >> 1) & 3)) * 8;

  f32x4 acc[MF][NF];
#pragma unroll
  for (int m = 0; m < MF; m++)
#pragma unroll
    for (int n = 0; n < NF; n++) acc[m][n] = (f32x4){0.f, 0.f, 0.f, 0.f};

  auto stage = [&](int bb, int kt) {
#pragma unroll
    for (int c = 0; c < CA; c++)
      gl_lds16(A + (size_t)(m0 + c * 64 + (t >> 2)) * K + (size_t)(kt * 32) +
                   uoff,
               &smem[bb * BM * 32 + c * 2048 + wid * 512]);
#pragma unroll
    for (int c = 0; c < CB; c++)
      gl_lds16(Bt + (size_t)(n0 + c * 64 + (t >> 2)) * K + (size_t)(kt * 32) +
                   uoff,
               &smem[3 * BM * 32 + bb * BN * 32 + c * 2048 + wid * 512]);
  };
  auto rdA = [&](int bb, int mf) {
    return *(const bf16x8*)&smem[bb * BM * 32 +
                                 (wr * (BM / 2) + mf * 16 + lr) * 32 + au];
  };
  auto rdB = [&](int bb, int nf) {
    return *(const bf16x8*)&smem[3 * BM * 32 + bb * BN * 32 +
                                 (wc * BWN + nf * 16 + lr) * 32 + au];
  };

  // prologue: stage tiles 0 and 1; wait for tile 0 only.
  stage(0, 0);
  if (nkt > 1) {
    stage(1, 1);
    if constexpr (SC == 4) asm volatile("s_waitcnt vmcnt(4)" ::: "memory");
    else                   asm volatile("s_waitcnt vmcnt(3)" ::: "memory");
  } else {
    asm volatile("s_waitcnt vmcnt(0)" ::: "memory");
  }
  SB(); __builtin_amdgcn_s_barrier(); SB();

  int rb = 0;
  for (int kt = 0; kt < nkt; kt++) {
    const int sb = (rb >= 1) ? rb - 1 : 2;  // (rb + 2) % 3
    const bool pf = (kt + 2 < nkt);
    if (pf) stage(sb, kt + 2);

    bf16x8 Br[NF];
#pragma unroll
    for (int nf = 0; nf < NF; nf++) Br[nf] = rdB(rb, nf);
    bf16x8 Ar[MF];
#pragma unroll
    for (int mf = 0; mf < MF; mf++) Ar[mf] = rdA(rb, mf);
    __builtin_amdgcn_s_setprio(1);
#pragma unroll
    for (int mf = 0; mf < MF; mf++)
#pragma unroll
      for (int nf = 0; nf < NF; nf++)
        acc[mf][nf] = __builtin_amdgcn_mfma_f32_16x16x32_bf16(
            Ar[mf], Br[nf], acc[mf][nf], 0, 0, 0);
    __builtin_amdgcn_s_setprio(0);

    if (pf) {
      if constexpr (SC == 4) asm volatile("s_waitcnt vmcnt(4)" ::: "memory");
      else                   asm volatile("s_waitcnt vmcnt(3)" ::: "memory");
    } else {
      asm volatile("s_waitcnt vmcnt(0)" ::: "memory");
    }
    SB(); __builtin_amdgcn_s_barrier(); SB();
    rb = (rb == 2) ? 0 : rb + 1;
  }

  // epilogue
#pragma unroll
  for (int mf = 0; mf < MF; mf++) {
#pragma unroll
    for (int nf = 0; nf < NF; nf++) {
      const int gr0 = m0 + wr * (BM / 2) + mf * 16 + lc * 4;
      const int gc = n0 + wc * BWN + nf * 16 + lr;
      const float bs = bias[gc];
#pragma unroll
      for (int r = 0; r < 4; r++) {
        const float v = acc[mf][nf][r] + bs;
        const int gr = gr0 + r;
        if (EPI == 0) {
          ((ushort*)outp)[(size_t)gr * N + gc] = f2bf(v);
        } else if (EPI == 1) {
          const float gg = 0.5f * v * (1.0f + erff(v * 0.70710678118654752f));
          ((ushort*)outp)[(size_t)gr * N + gc] = f2bf(gg);
        } else {
          ((float*)outp)[(size_t)gr * N + gc] =
              v + resid[(size_t)gr * N + gc];
        }
      }
    }
  }
}

// ---------- flash attention (swapped operands) ----------
__global__ __launch_bounds__(256) void attn_kernel(
    const ushort* __restrict__ qkv, const ushort* __restrict__ vt,
    ushort* __restrict__ o_out) {
  __shared__ ushort sK[4096];
  __shared__ ushort sV[4096];
  __shared__ ushort sP[4 * 32 * 72];
  const int t = threadIdx.x;
  const int lane = t & 63, wid = t >> 6;
  const int lr = lane & 15, lc = lane >> 4;
  const int qb = blockIdx.x;
  const int bh = blockIdx.y;
  const int bidx = bh >> 4, h = bh & 15;
  const size_t base = (size_t)bidx * 1024 * 3072;
  const int q0w = qb * 128 + wid * 32;

  bf16x8 qf[2][2];
#pragma unroll
  for (int nf = 0; nf < 2; nf++)
#pragma unroll
    for (int kd = 0; kd < 2; kd++)
      qf[nf][kd] = *(const bf16x8*)&qkv[base +
          (size_t)(q0w + nf * 16 + lr) * 3072 + h * 64 + kd * 32 + lc * 8];

  f32x4 oacc[4][2];
#pragma unroll
  for (int mf = 0; mf < 4; mf++)
#pragma unroll
    for (int nf = 0; nf < 2; nf++) oacc[mf][nf] = (f32x4){0.f, 0.f, 0.f, 0.f};
  float m_r[2] = {-1e30f, -1e30f};
  float l_r[2] = {0.f, 0.f};

  const int srow = lane >> 2;
  const int scol = (lane & 3) * 8;
  ushort* pw = sP + wid * 2304;

  for (int kv0 = 0; kv0 < 1024; kv0 += 64) {
    __syncthreads();
#pragma unroll
    for (int s = 0; s < 2; s++) {
      gl_lds16(qkv + base + (size_t)(kv0 + wid * 16 + srow) * 3072 + 1024 +
                   h * 64 + s * 32 + scol,
               sK + s * 2048 + wid * 512);
      gl_lds16(vt + (size_t)(bh * 64 + wid * 16 + srow) * 1024 + kv0 + s * 32 +
                   scol,
               sV + s * 2048 + wid * 512);
    }
    __syncthreads();

    f32x4 st[4][2];
#pragma unroll
    for (int mf = 0; mf < 4; mf++) {
      bf16x8 ka0 = *(const bf16x8*)&sK[(mf * 16 + lr) * 32 + lc * 8];
      bf16x8 ka1 = *(const bf16x8*)&sK[2048 + (mf * 16 + lr) * 32 + lc * 8];
#pragma unroll
      for (int nf = 0; nf < 2; nf++) {
        f32x4 z = (f32x4){0.f, 0.f, 0.f, 0.f};
        z = __builtin_amdgcn_mfma_f32_16x16x32_bf16(ka0, qf[nf][0], z, 0, 0, 0);
        z = __builtin_amdgcn_mfma_f32_16x16x32_bf16(ka1, qf[nf][1], z, 0, 0, 0);
        st[mf][nf] = z;
      }
    }

#pragma unroll
    for (int nf = 0; nf < 2; nf++) {
      float mx = st[0][nf][0];
#pragma unroll
      for (int mf = 0; mf < 4; mf++)
        mx = fmaxf(mx, fmaxf(fmaxf(st[mf][nf][0], st[mf][nf][1]),
                             fmaxf(st[mf][nf][2], st[mf][nf][3])));
      mx = fmaxf(mx, __shfl_xor(mx, 16));
      mx = fmaxf(mx, __shfl_xor(mx, 32));
      mx *= 0.125f;
      const float mn = fmaxf(m_r[nf], mx);
      const float alpha = __expf(m_r[nf] - mn);
      m_r[nf] = mn;
      float rs = 0.f;
#pragma unroll
      for (int mf = 0; mf < 4; mf++) {
        const float p0 = __expf(fmaf(st[mf][nf][0], 0.125f, -mn));
        const float p1 = __expf(fmaf(st[mf][nf][1], 0.125f, -mn));
        const float p2 = __expf(fmaf(st[mf][nf][2], 0.125f, -mn));
        const float p3 = __expf(fmaf(st[mf][nf][3], 0.125f, -mn));
        rs += (p0 + p1) + (p2 + p3);
        uint2 u;
        u.x = (uint)f2bf(p0) | ((uint)f2bf(p1) << 16);
        u.y = (uint)f2bf(p2) | ((uint)f2bf(p3) << 16);
        *(uint2*)&pw[(nf * 16 + lr) * 72 + mf * 16 + lc * 4] = u;
      }
      rs += __shfl_xor(rs, 16);
      rs += __shfl_xor(rs, 32);
      l_r[nf] = l_r[nf] * alpha + rs;
#pragma unroll
      for (int mf = 0; mf < 4; mf++) {
        oacc[mf][nf][0] *= alpha;
        oacc[mf][nf][1] *= alpha;
        oacc[mf][nf][2] *= alpha;
        oacc[mf][nf][3] *= alpha;
      }
    }

#pragma unroll
    for (int ks = 0; ks < 2; ks++) {
      bf16x8 pb0 = *(const bf16x8*)&pw[lr * 72 + ks * 32 + lc * 8];
      bf16x8 pb1 = *(const bf16x8*)&pw[(16 + lr) * 72 + ks * 32 + lc * 8];
#pragma unroll
      for (int mf = 0; mf < 4; mf++) {
        bf16x8 va = *(const bf16x8*)&sV[ks * 2048 + (mf * 16 + lr) * 32 + lc * 8];
        oacc[mf][0] =
            __builtin_amdgcn_mfma_f32_16x16x32_bf16(va, pb0, oacc[mf][0], 0, 0, 0);
        oacc[mf][1] =
            __builtin_amdgcn_mfma_f32_16x16x32_bf16(va, pb1, oacc[mf][1], 0, 0, 0);
      }
    }
  }

  const float inv[2] = {1.f / l_r[0], 1.f / l_r[1]};
#pragma unroll
  for (int mf = 0; mf < 4; mf++)
#pragma unroll
    for (int nf = 0; nf < 2; nf++) {
      ushort4 o4;
      o4.x = f2bf(oacc[mf][nf][0] * inv[nf]);
      o4.y = f2bf(oacc[mf][nf][1] * inv[nf]);
      o4.z = f2bf(oacc[mf][nf][2] * inv[nf]);
      o4.w = f2bf(oacc[mf][nf][3] * inv[nf]);
      *(ushort4*)&o_out[(size_t)(bidx * 1024 + q0w + nf * 16 + lr) * 1024 +
                        h * 64 + mf * 16 + lc * 4] = o4;
    }
}

// ---------- launch ----------
extern "C" void kernel_launch(void* const* d_in, const int* in_sizes, int n_in,
                              void* d_out, int out_size, void* d_ws,
                              size_t ws_size, hipStream_t stream) {
  const float* x      = (const float*)d_in[0];
  const float* ln1_g  = (const float*)d_in[1];
  const float* ln1_b  = (const float*)d_in[2];
  const float* w_qkv  = (const float*)d_in[3];
  const float* b_qkv  = (const float*)d_in[4];
  const float* w_proj = (const float*)d_in[5];
  const float* b_proj = (const float*)d_in[6];
  const float* ln2_g  = (const float*)d_in[7];
  const float* ln2_b  = (const float*)d_in[8];
  const float* w_fc1  = (const float*)d_in[9];
  const float* b_fc1  = (const float*)d_in[10];
  const float* w_fc2  = (const float*)d_in[11];
  const float* b_fc2  = (const float*)d_in[12];
  float* out = (float*)d_out;

  ushort* ws      = (ushort*)d_ws;
  ushort* wt_qkv  = ws;                         // 3072*1024
  ushort* wt_proj = wt_qkv + 3072 * 1024;       // 1024*1024
  ushort* wt_fc1  = wt_proj + 1024 * 1024;      // 4096*1024
  ushort* wt_fc2  = wt_fc1 + 4096 * 1024;       // 1024*4096
  ushort* hbuf    = wt_fc2 + 1024 * 4096;       // 4096*1024
  ushort* qkv     = hbuf + 4096 * 1024;         // 4096*3072
  ushort* obuf    = qkv + 4096 * 3072;          // 4096*1024
  ushort* h3      = qkv;                        // aliases qkv+obuf
  ushort* vtb     = hbuf;                       // vt[64][64][1024]

  transpose_w<<<dim3(96, 32), dim3(32, 8), 0, stream>>>(w_qkv, wt_qkv, 1024, 3072);
  transpose_w<<<dim3(32, 32), dim3(32, 8), 0, stream>>>(w_proj, wt_proj, 1024, 1024);
  transpose_w<<<dim3(128, 32), dim3(32, 8), 0, stream>>>(w_fc1, wt_fc1, 1024, 4096);
  transpose_w<<<dim3(32, 128), dim3(32, 8), 0, stream>>>(w_fc2, wt_fc2, 4096, 1024);

  ln_bf16<<<4096, 256, 0, stream>>>(x, ln1_g, ln1_b, hbuf);
  // QKV: 128^2, grid 24x32=768. XCD rect 12x8, 2 across. LDS 48KB (3/CU).
  gemm3b<128, 128, 4, 3, 0><<<dim3(24, 32), 256, 0, stream>>>(
      hbuf, wt_qkv, b_qkv, nullptr, qkv, 4096, 3072, 1024, 12, 8, 2);
  transpose_v<<<dim3(32, 2, 64), dim3(32, 8), 0, stream>>>(qkv, vtb);
  attn_kernel<<<dim3(8, 64), 256, 0, stream>>>(qkv, vtb, obuf);
  // proj + residual: 128x64, grid 16x32=512. LDS 36KB (4/CU).
  gemm3b<128, 64, 4, 4, 2><<<dim3(16, 32), 256, 0, stream>>>(
      obuf, wt_proj, b_proj, x, out, 4096, 1024, 1024, 8, 8, 2);
  ln_bf16<<<4096, 256, 0, stream>>>(out, ln2_g, ln2_b, hbuf);
  // fc1 + GELU: 128^2, grid 32x32=1024. XCD rect 16x8, 2 across.
  gemm3b<128, 128, 4, 3, 1><<<dim3(32, 32), 256, 0, stream>>>(
      hbuf, wt_fc1, b_fc1, nullptr, h3, 4096, 4096, 1024, 16, 8, 2);
  // fc2 + residual: 128x64, grid 16x32=512.
  gemm3b<128, 64, 4, 4, 2><<<dim3(16, 32), 256, 0, stream>>>(
      h3, wt_fc2, b_fc2, out, out, 4096, 1024, 4096, 8, 8, 2);
}